// Round 8
// baseline (95.875 us; speedup 1.0000x reference)
//
#include <hip/hip_runtime.h>

#define ETA 0.1f
#define BATCH 4
#define SEQ 2048
#define DMODEL 1024
#define NH 8
#define DHEAD 64
#define HD 512   // NH*DHEAD
#define QKVW 1536
#define CH 64    // chunk length
#define NCH (SEQ / CH)  // 32

typedef float f32x4 __attribute__((ext_vector_type(4)));
typedef short short8 __attribute__((ext_vector_type(8)));
typedef short short4v __attribute__((ext_vector_type(4)));

static __device__ __forceinline__ ushort f2bf(float f) {
  union { float f; unsigned u; } x; x.f = f;
  unsigned r = (x.u + 0x7fffu + ((x.u >> 16) & 1u)) >> 16;
  return (ushort)r;
}
static __device__ __forceinline__ float bf2f(ushort u) {
  union { unsigned u; float f; } x; x.u = ((unsigned)u) << 16;
  return x.f;
}

#define GLDS16(g, l)                                                    \
  __builtin_amdgcn_global_load_lds(                                     \
      (const __attribute__((address_space(1))) unsigned int*)(const void*)(g), \
      (__attribute__((address_space(3))) unsigned int*)(void*)(l), 16, 0, 0)

// ---------------------------------------------------------------------------
// conv: merged input/weight conversion.
//   blocks [0,2048): x f32 -> xb bf16 (16 elems/thread)
//   blocks [2048,4096): weight transpose+convert (Wq/Wk/Wv -> Wt, Wo -> Wot)
// ---------------------------------------------------------------------------
__global__ __launch_bounds__(256) void conv_kernel(
    const float* __restrict__ x, const float* __restrict__ Wq,
    const float* __restrict__ Wk, const float* __restrict__ Wv,
    const float* __restrict__ Wo, ushort* __restrict__ xb,
    ushort* __restrict__ Wt, ushort* __restrict__ Wot) {
  const int tid = threadIdx.x;
  __shared__ float T[32][33];
  if (blockIdx.x < 2048) {
    size_t i = ((size_t)blockIdx.x * 256 + tid) * 16;
    ushort t[16];
#pragma unroll
    for (int u = 0; u < 4; ++u) {
      f32x4 v = *(const f32x4*)&x[i + u * 4];
#pragma unroll
      for (int e = 0; e < 4; ++e) t[u * 4 + e] = f2bf(v[e]);
    }
    *(short8*)&xb[i] = *(short8*)&t[0];
    *(short8*)&xb[i + 8] = *(short8*)&t[8];
    return;
  }
  const int idx = blockIdx.x - 2048;
  const int m = idx >> 9;          // 0..3
  const int bx = idx & 511;
  const float* src;
  ushort* dst;
  int srcN, dstK, k0, n0, rowOff;
  if (m < 3) {
    src = (m == 0) ? Wq : ((m == 1) ? Wk : Wv);
    srcN = 512; dstK = 1024;
    k0 = (bx >> 4) << 5; n0 = (bx & 15) << 5;
    dst = Wt; rowOff = m * 512;
  } else {
    src = Wo; srcN = 1024; dstK = 512;
    k0 = (bx >> 5) << 5; n0 = (bx & 31) << 5;
    dst = Wot; rowOff = 0;
  }
  const int r = tid >> 3, c4 = (tid & 7) << 2;
  f32x4 v = *(const f32x4*)&src[(size_t)(k0 + r) * srcN + n0 + c4];
  T[r][c4 + 0] = v[0]; T[r][c4 + 1] = v[1];
  T[r][c4 + 2] = v[2]; T[r][c4 + 3] = v[3];
  __syncthreads();
  short4v o;
#pragma unroll
  for (int e = 0; e < 4; ++e) o[e] = (short)f2bf(T[c4 + e][r]);
  *(short4v*)&dst[(size_t)(rowOff + n0 + r) * dstK + k0 + c4] = o;
}

// ---------------------------------------------------------------------------
// GEMM: C[M][N] = A[M][K] @ Bt[N][K]^T, bf16 in.  BM=BN=128, BK=32,
// 256 threads (4 waves, 2x2), 3 LDS buffers / 2 tiles in flight,
// single barrier per K-step, counted vmcnt, XOR bank swizzle.
// ---------------------------------------------------------------------------
template <bool OUT_BF16>
__global__ __launch_bounds__(256, 3) void gemm_bt_kernel(
    const ushort* __restrict__ A, const ushort* __restrict__ Bt,
    void* __restrict__ Cv, const float* __restrict__ bias,
    int M, int N, int K) {
  const int tiles_n = N >> 7;
  const int nwg = gridDim.x;
  const int bid = blockIdx.x;
  const int swz = (bid & 7) * (nwg >> 3) + (bid >> 3);
  const int bm = swz / tiles_n;
  const int bn = swz % tiles_n;
  const int tid = threadIdx.x;
  const int w = tid >> 6, lane = tid & 63;
  const int wr = w >> 1, wc = w & 1;
  const int fr = lane & 15, fq = lane >> 4;

  __shared__ ushort As[3][128][32];
  __shared__ ushort Bs[3][128][32];

  f32x4 acc[4][4];
#pragma unroll
  for (int mi = 0; mi < 4; ++mi)
#pragma unroll
    for (int ni = 0; ni < 4; ++ni) acc[mi][ni] = f32x4{0.f, 0.f, 0.f, 0.f};

  const int lw = lane >> 2;
  const int scz = ((lane & 3) ^ ((lane >> 3) & 3)) << 3;
  const ushort* ga = A + (size_t)(bm * 128 + w * 32 + lw) * K + scz;
  const ushort* gb = Bt + (size_t)(bn * 128 + w * 32 + lw) * K + scz;
  const size_t rstep = (size_t)16 * K;

  const int nt = K >> 5;

#pragma unroll
  for (int pt = 0; pt < 2; ++pt) {
    ushort* la = &As[pt][w * 32][0];
    ushort* lb = &Bs[pt][w * 32][0];
    GLDS16(ga + pt * 32, la);
    GLDS16(ga + pt * 32 + rstep, la + 512);
    GLDS16(gb + pt * 32, lb);
    GLDS16(gb + pt * 32 + rstep, lb + 512);
  }

  const int fqs8 = (fq ^ ((fr >> 1) & 3)) * 8;

  for (int t = 0; t < nt; ++t) {
    if (t < nt - 1) {
      asm volatile("s_waitcnt vmcnt(4) lgkmcnt(0)\n\ts_barrier" ::: "memory");
    } else {
      asm volatile("s_waitcnt vmcnt(0) lgkmcnt(0)\n\ts_barrier" ::: "memory");
    }
    if (t + 2 < nt) {
      const int sb = (t + 2) % 3;
      const int kt = (t + 2) << 5;
      ushort* la = &As[sb][w * 32][0];
      ushort* lb = &Bs[sb][w * 32][0];
      GLDS16(ga + kt, la);
      GLDS16(ga + kt + rstep, la + 512);
      GLDS16(gb + kt, lb);
      GLDS16(gb + kt + rstep, lb + 512);
    }
    const int cb = t % 3;
    short8 a[4], b[4];
#pragma unroll
    for (int mi = 0; mi < 4; ++mi)
      a[mi] = *(const short8*)&As[cb][wr * 64 + mi * 16 + fr][fqs8];
#pragma unroll
    for (int ni = 0; ni < 4; ++ni)
      b[ni] = *(const short8*)&Bs[cb][wc * 64 + ni * 16 + fr][fqs8];
#pragma unroll
    for (int mi = 0; mi < 4; ++mi)
#pragma unroll
      for (int ni = 0; ni < 4; ++ni)
        acc[mi][ni] = __builtin_amdgcn_mfma_f32_16x16x32_bf16(
            a[mi], b[ni], acc[mi][ni], 0, 0, 0);
  }

#pragma unroll
  for (int ni = 0; ni < 4; ++ni) {
    const int gc = bn * 128 + wc * 64 + ni * 16 + fr;
    float badd = (!OUT_BF16 && bias) ? bias[gc] : 0.f;
#pragma unroll
    for (int mi = 0; mi < 4; ++mi) {
#pragma unroll
      for (int r = 0; r < 4; ++r) {
        const int gr = bm * 128 + wr * 64 + mi * 16 + fq * 4 + r;
        if (OUT_BF16) {
          ((ushort*)Cv)[(size_t)gr * N + gc] = f2bf(acc[mi][ni][r]);
        } else {
          ((float*)Cv)[(size_t)gr * N + gc] = acc[mi][ni][r] + badd;
        }
      }
    }
  }
}

// ---------------------------------------------------------------------------
// intraS: per (b,h,chunk) compute S_c = ETA*cl * K^T @ (V/cum)  (bf16 out).
// ---------------------------------------------------------------------------
__global__ __launch_bounds__(256) void intraS_kernel(
    const ushort* __restrict__ qkv, const float* __restrict__ gamma,
    ushort* __restrict__ S, float* __restrict__ clb) {
  const int bx = blockIdx.x;
  const int c = bx & (NCH - 1);
  const int h = (bx >> 5) & (NH - 1);
  const int b = bx >> 8;
  const int tid = threadIdx.x;
  const int w = tid >> 6, lane = tid & 63;
  const int fr = lane & 15, fq = lane >> 4;

  __shared__ ushort KT[64][72];
  __shared__ ushort VT[64][72];
  __shared__ float cumS[64];

  const int p = tid >> 2, d0 = (tid & 3) * 16;
  const ushort* base = &qkv[((size_t)b * SEQ + c * CH + p) * QKVW + h * 64 + d0];
  short8 k0 = *(const short8*)(base + 512);
  short8 k1 = *(const short8*)(base + 520);
  short8 v0 = *(const short8*)(base + 1024);
  short8 v1 = *(const short8*)(base + 1032);

  {
    float g = gamma[(size_t)b * SEQ + c * CH + lane];
    float prod = expf(-fminf(g, 10.f));
#pragma unroll
    for (int off = 1; off < 64; off <<= 1) {
      float o = __shfl_up(prod, off);
      if (lane >= off) prod *= o;
    }
    cumS[lane] = prod;
  }
  __syncthreads();

  {
    const float rc = 1.f / cumS[p];
#pragma unroll
    for (int j = 0; j < 8; ++j) {
      KT[d0 + j][p] = (ushort)k0[j];
      KT[d0 + 8 + j][p] = (ushort)k1[j];
      VT[d0 + j][p] = f2bf(bf2f((ushort)v0[j]) * rc);
      VT[d0 + 8 + j][p] = f2bf(bf2f((ushort)v1[j]) * rc);
    }
  }
  __syncthreads();

  const float scl = ETA * cumS[63];
  const int arow = w * 16 + fr;
  short8 ka0 = *(const short8*)&KT[arow][fq * 8];
  short8 ka1 = *(const short8*)&KT[arow][32 + fq * 8];
  ushort* Sp = &S[(((size_t)(b * NH + h)) * NCH + c) << 12];
#pragma unroll
  for (int cf = 0; cf < 4; ++cf) {
    short8 bv0 = *(const short8*)&VT[cf * 16 + fr][fq * 8];
    short8 bv1 = *(const short8*)&VT[cf * 16 + fr][32 + fq * 8];
    f32x4 accS = {0.f, 0.f, 0.f, 0.f};
    accS = __builtin_amdgcn_mfma_f32_16x16x32_bf16(ka0, bv0, accS, 0, 0, 0);
    accS = __builtin_amdgcn_mfma_f32_16x16x32_bf16(ka1, bv1, accS, 0, 0, 0);
#pragma unroll
    for (int r = 0; r < 4; ++r) {
      int row = w * 16 + fq * 4 + r;
      int col = cf * 16 + fr;
      Sp[row * 64 + col] = f2bf(accS[r] * scl);
    }
  }
  if (tid == 0 && h == 0) clb[b * NCH + c] = cumS[63];
}

// ---------------------------------------------------------------------------
// intraY (prop folded in): per (b,h,chunk):
//   stash = (prod_{j<c} cl_j)*state0 + sum_{cc<c} (prod_{cc<j<c} cl_j)*S_cc
//   P = mask(cum*q @ (v/cum)^T)*ETA ;  y = P @ K + (cum*q) @ stash^T
//   c==NCH-1 additionally writes state_out = cl_c*stash + S_c (f32).
// ---------------------------------------------------------------------------
__global__ __launch_bounds__(256) void intraY_kernel(
    const ushort* __restrict__ qkv, const float* __restrict__ gamma,
    const ushort* __restrict__ S, const float* __restrict__ clb,
    const float* __restrict__ state0, ushort* __restrict__ ybf,
    float* __restrict__ state_out) {
  const int bx = blockIdx.x;
  const int c = bx & (NCH - 1);
  const int h = (bx >> 5) & (NH - 1);
  const int b = bx >> 8;
  const int bh = b * NH + h;
  const int tid = threadIdx.x;
  const int w = tid >> 6, lane = tid & 63;
  const int fr = lane & 15, fq = lane >> 4;

  __shared__ ushort Qs[64][72];   // cum[p]*q
  __shared__ ushort Vs[64][72];   // v/cum
  __shared__ ushort KT[64][72];   // k transposed
  __shared__ ushort Ps[64][72];   // masked scores
  __shared__ ushort Bst[64][72];  // stash (bf16)
  __shared__ float cumS[64];
  __shared__ float prodS[32];     // prodS[l] = prod_{j=l}^{31} pl[j], pl[j]=cl[j] if j<c else 1

  const int p = tid >> 2, d0 = (tid & 3) * 16;
  const ushort* base = &qkv[((size_t)b * SEQ + c * CH + p) * QKVW + h * 64 + d0];
  short8 q0 = *(const short8*)base;
  short8 q1 = *(const short8*)(base + 8);
  short8 k0 = *(const short8*)(base + 512);
  short8 k1 = *(const short8*)(base + 520);
  short8 v0 = *(const short8*)(base + 1024);
  short8 v1 = *(const short8*)(base + 1032);

  // gamma inclusive prefix product (all waves redundant, identical writes)
  {
    float g = gamma[(size_t)b * SEQ + c * CH + lane];
    float prod = expf(-fminf(g, 10.f));
#pragma unroll
    for (int off = 1; off < 64; off <<= 1) {
      float o = __shfl_up(prod, off);
      if (lane >= off) prod *= o;
    }
    cumS[lane] = prod;
  }
  // chunk-decay suffix products (wave 0, lanes 0..31)
  if (tid < 32) {
    float pl = (tid < c) ? clb[b * NCH + tid] : 1.f;
    float prod = pl;
#pragma unroll
    for (int off = 1; off < 32; off <<= 1) {
      float o = __shfl_down(prod, off);
      if (tid + off < 32) prod *= o;
    }
    prodS[tid] = prod;
  }
  __syncthreads();

  // ---- stash accumulation in f32 (this thread's 16 elems: row p, cols d0..)
  float sa[16], sa2[16];
  {
    const float pre0 = prodS[0];
    const float* s0p = &state0[((size_t)bh * 64 + p) * 64 + d0];
#pragma unroll
    for (int u = 0; u < 4; ++u) {
      f32x4 sv = *(const f32x4*)&s0p[u * 4];
#pragma unroll
      for (int e = 0; e < 4; ++e) { sa[u * 4 + e] = pre0 * sv[e]; sa2[u * 4 + e] = 0.f; }
    }
    const ushort* Sbase = S + (((size_t)bh * NCH) << 12) + (size_t)p * 64 + d0;
    int cc = 0;
    for (; cc + 1 < c; cc += 2) {
      short8 ea = *(const short8*)(Sbase + ((size_t)cc << 12));
      short8 eb = *(const short8*)(Sbase + ((size_t)cc << 12) + 8);
      short8 fa = *(const short8*)(Sbase + ((size_t)(cc + 1) << 12));
      short8 fb = *(const short8*)(Sbase + ((size_t)(cc + 1) << 12) + 8);
      float wa = prodS[cc + 1];
      float wb = (cc + 2 < 32) ? prodS[cc + 2] : 1.f;
#pragma unroll
      for (int j = 0; j < 8; ++j) {
        sa[j]      += wa * bf2f((ushort)ea[j]);
        sa[8 + j]  += wa * bf2f((ushort)eb[j]);
        sa2[j]     += wb * bf2f((ushort)fa[j]);
        sa2[8 + j] += wb * bf2f((ushort)fb[j]);
      }
    }
    if (cc < c) {
      short8 ea = *(const short8*)(Sbase + ((size_t)cc << 12));
      short8 eb = *(const short8*)(Sbase + ((size_t)cc << 12) + 8);
      float wa = (cc + 1 < 32) ? prodS[cc + 1] : 1.f;
#pragma unroll
      for (int j = 0; j < 8; ++j) {
        sa[j]     += wa * bf2f((ushort)ea[j]);
        sa[8 + j] += wa * bf2f((ushort)eb[j]);
      }
    }
#pragma unroll
    for (int j = 0; j < 16; ++j) sa[j] += sa2[j];
  }

  // ---- stage LDS
  {
    const float cp = cumS[p];
    const float rc = 1.f / cp;
    ushort tq[16], tv[16], ts[16];
#pragma unroll
    for (int j = 0; j < 8; ++j) {
      tq[j]     = f2bf(bf2f((ushort)q0[j]) * cp);
      tq[8 + j] = f2bf(bf2f((ushort)q1[j]) * cp);
      tv[j]     = f2bf(bf2f((ushort)v0[j]) * rc);
      tv[8 + j] = f2bf(bf2f((ushort)v1[j]) * rc);
      KT[d0 + j][p] = (ushort)k0[j];
      KT[d0 + 8 + j][p] = (ushort)k1[j];
    }
#pragma unroll
    for (int j = 0; j < 16; ++j) ts[j] = f2bf(sa[j]);
    *(short8*)&Qs[p][d0] = *(short8*)&tq[0];
    *(short8*)&Qs[p][d0 + 8] = *(short8*)&tq[8];
    *(short8*)&Vs[p][d0] = *(short8*)&tv[0];
    *(short8*)&Vs[p][d0 + 8] = *(short8*)&tv[8];
    *(short8*)&Bst[p][d0] = *(short8*)&ts[0];
    *(short8*)&Bst[p][d0 + 8] = *(short8*)&ts[8];
  }
  __syncthreads();

  const int arow = w * 16 + fr;
  short8 a0 = *(const short8*)&Qs[arow][fq * 8];
  short8 a1 = *(const short8*)&Qs[arow][32 + fq * 8];

  // mm1: P[p][s] = mask(s<=p) * ETA * (cum q) @ (v/cum)^T
#pragma unroll
  for (int cf = 0; cf < 4; ++cf) {
    f32x4 acc = {0.f, 0.f, 0.f, 0.f};
    if (cf <= w) {
      short8 b0 = *(const short8*)&Vs[cf * 16 + fr][fq * 8];
      short8 b1 = *(const short8*)&Vs[cf * 16 + fr][32 + fq * 8];
      acc = __builtin_amdgcn_mfma_f32_16x16x32_bf16(a0, b0, acc, 0, 0, 0);
      acc = __builtin_amdgcn_mfma_f32_16x16x32_bf16(a1, b1, acc, 0, 0, 0);
    }
#pragma unroll
    for (int r = 0; r < 4; ++r) {
      int pi = w * 16 + fq * 4 + r, si = cf * 16 + fr;
      Ps[pi][si] = f2bf((si <= pi) ? acc[r] * ETA : 0.f);
    }
  }
  __syncthreads();

  // y = P @ K + Qs @ stash^T
  short8 p0 = *(const short8*)&Ps[arow][fq * 8];
  short8 p1 = *(const short8*)&Ps[arow][32 + fq * 8];
  const size_t yrow0 = (size_t)b * SEQ + c * CH;
#pragma unroll
  for (int cf = 0; cf < 4; ++cf) {
    f32x4 accY = {0.f, 0.f, 0.f, 0.f};
    short8 bs0 = *(const short8*)&Bst[cf * 16 + fr][fq * 8];
    short8 bs1 = *(const short8*)&Bst[cf * 16 + fr][32 + fq * 8];
    accY = __builtin_amdgcn_mfma_f32_16x16x32_bf16(a0, bs0, accY, 0, 0, 0);
    accY = __builtin_amdgcn_mfma_f32_16x16x32_bf16(a1, bs1, accY, 0, 0, 0);
    short8 bk0 = *(const short8*)&KT[cf * 16 + fr][fq * 8];
    short8 bk1 = *(const short8*)&KT[cf * 16 + fr][32 + fq * 8];
    accY = __builtin_amdgcn_mfma_f32_16x16x32_bf16(p0, bk0, accY, 0, 0, 0);
    accY = __builtin_amdgcn_mfma_f32_16x16x32_bf16(p1, bk1, accY, 0, 0, 0);
#pragma unroll
    for (int r = 0; r < 4; ++r) {
      int row = w * 16 + fq * 4 + r;
      int col = cf * 16 + fr;
      ybf[(yrow0 + row) * HD + h * 64 + col] = f2bf(accY[r]);
    }
  }

  // final state (only chunk NCH-1 blocks): state_out = cl_c*stash + S_c
  if (c == NCH - 1) {
    const float clv = clb[b * NCH + c];
    const ushort* Sc = S + (((size_t)bh * NCH + c) << 12) + (size_t)p * 64 + d0;
    short8 ea = *(const short8*)Sc;
    short8 eb = *(const short8*)(Sc + 8);
    float* so = &state_out[((size_t)bh * 64 + p) * 64 + d0];
#pragma unroll
    for (int u = 0; u < 4; ++u) {
      f32x4 ov;
#pragma unroll
      for (int e = 0; e < 4; ++e) {
        int j = u * 4 + e;
        float sj = (j < 8) ? bf2f((ushort)ea[j]) : bf2f((ushort)eb[j - 8]);
        ov[e] = clv * sa[j] + sj;
      }
      *(f32x4*)&so[u * 4] = ov;
    }
  }
}

extern "C" void kernel_launch(void* const* d_in, const int* in_sizes, int n_in,
                              void* d_out, int out_size, void* d_ws, size_t ws_size,
                              hipStream_t stream) {
  const float* x      = (const float*)d_in[0];
  const float* gamma  = (const float*)d_in[1];
  const float* state0 = (const float*)d_in[2];
  const float* Wq     = (const float*)d_in[3];
  const float* Wk     = (const float*)d_in[4];
  const float* Wv     = (const float*)d_in[5];
  const float* Wo     = (const float*)d_in[6];
  const float* bo     = (const float*)d_in[7];

  float* out = (float*)d_out;
  float* state_out = out + (size_t)BATCH * SEQ * DMODEL;

  const int M = BATCH * SEQ;  // 8192

  ushort* xb  = (ushort*)d_ws;                       // [8192][1024]
  ushort* wt  = xb + (size_t)M * DMODEL;             // [1536][1024]
  ushort* wot = wt + (size_t)QKVW * DMODEL;          // [1024][512]
  ushort* qkv = wot + (size_t)DMODEL * HD;           // [8192][1536]
  ushort* ybf = qkv + (size_t)M * QKVW;              // [8192][512]
  ushort* Sb  = ybf + (size_t)M * HD;                // [32][32][4096] bf16
  float*  clb = (float*)(Sb + (size_t)BATCH * NH * NCH * 4096);

  dim3 blk(256);

  conv_kernel<<<dim3(4096), blk, 0, stream>>>(x, Wq, Wk, Wv, Wo, xb, wt, wot);

  gemm_bt_kernel<true><<<dim3((M / 128) * (QKVW / 128)), blk, 0, stream>>>(
      xb, wt, qkv, nullptr, M, QKVW, DMODEL);

  intraS_kernel<<<dim3(BATCH * NH * NCH), blk, 0, stream>>>(
      qkv, gamma, Sb, clb);
  intraY_kernel<<<dim3(BATCH * NH * NCH), blk, 0, stream>>>(
      qkv, gamma, Sb, clb, state0, ybf, state_out);

  gemm_bt_kernel<false><<<dim3((M / 128) * (DMODEL / 128)), blk, 0, stream>>>(
      ybf, wot, out, bo, M, DMODEL, HD);
}

// Round 9
// 94.369 us; speedup vs baseline: 1.0160x; 1.0160x over previous
//
#include <hip/hip_runtime.h>
#include <hip/hip_bf16.h>

#define ETA 0.1f
#define BATCH 4
#define SEQ 2048
#define DMODEL 1024
#define NH 8
#define DHEAD 64
#define HD 512   // NH*DHEAD
#define QKVW 1536
#define CH 64    // chunk length
#define NCH (SEQ / CH)  // 32

typedef float f32x4 __attribute__((ext_vector_type(4)));
typedef short short8 __attribute__((ext_vector_type(8)));
typedef short short4v __attribute__((ext_vector_type(4)));

static __device__ __forceinline__ ushort f2bf(float f) {
  union { float f; unsigned u; } x; x.f = f;
  unsigned r = (x.u + 0x7fffu + ((x.u >> 16) & 1u)) >> 16;
  return (ushort)r;
}
static __device__ __forceinline__ float bf2f(ushort u) {
  union { unsigned u; float f; } x; x.u = ((unsigned)u) << 16;
  return x.f;
}
static __device__ __forceinline__ ushort f2bh(float f) {
  union { __hip_bfloat16 h; ushort u; } x;
  x.h = __float2bfloat16(f);  // hw RNE, bit-identical to f2bf
  return x.u;
}

#define GLDS16(g, l)                                                    \
  __builtin_amdgcn_global_load_lds(                                     \
      (const __attribute__((address_space(1))) unsigned int*)(const void*)(g), \
      (__attribute__((address_space(3))) unsigned int*)(void*)(l), 16, 0, 0)

// ---------------------------------------------------------------------------
// conv: weight transpose+convert only (x is consumed f32 by gemm_qkv now).
//   blocks m=idx>>9: 0..2 Wq/Wk/Wv -> Wt ; 3: Wo -> Wot
// ---------------------------------------------------------------------------
__global__ __launch_bounds__(256) void conv_kernel(
    const float* __restrict__ Wq, const float* __restrict__ Wk,
    const float* __restrict__ Wv, const float* __restrict__ Wo,
    ushort* __restrict__ Wt, ushort* __restrict__ Wot) {
  const int tid = threadIdx.x;
  __shared__ float T[32][33];
  const int idx = blockIdx.x;
  const int m = idx >> 9;          // 0..3
  const int bx = idx & 511;
  const float* src;
  ushort* dst;
  int srcN, dstK, k0, n0, rowOff;
  if (m < 3) {
    src = (m == 0) ? Wq : ((m == 1) ? Wk : Wv);
    srcN = 512; dstK = 1024;
    k0 = (bx >> 4) << 5; n0 = (bx & 15) << 5;
    dst = Wt; rowOff = m * 512;
  } else {
    src = Wo; srcN = 1024; dstK = 512;
    k0 = (bx >> 5) << 5; n0 = (bx & 31) << 5;
    dst = Wot; rowOff = 0;
  }
  const int r = tid >> 3, c4 = (tid & 7) << 2;
  f32x4 v = *(const f32x4*)&src[(size_t)(k0 + r) * srcN + n0 + c4];
  T[r][c4 + 0] = v[0]; T[r][c4 + 1] = v[1];
  T[r][c4 + 2] = v[2]; T[r][c4 + 3] = v[3];
  __syncthreads();
  short4v o;
#pragma unroll
  for (int e = 0; e < 4; ++e) o[e] = (short)f2bf(T[c4 + e][r]);
  *(short4v*)&dst[(size_t)(rowOff + n0 + r) * dstK + k0 + c4] = o;
}

// ---------------------------------------------------------------------------
// gemm_qkv: C[M][N](bf16) = A[M][K](f32, converted in-flight) @ Bt[N][K]^T.
// BM=BN=128, BK=32, 256 threads (4 waves 2x2). A: reg-staged (4x f32x4,
// hw cvt, 2x ds_write_b128, XOR-swizzled); B: global_load_lds, pre-swizzled
// global source. 3 LDS bufs; A-loads 3 iters ahead (2 reg slots, static via
// 2x-unrolled loop), B glds 2 ahead; steady wait vmcnt(6)+lgkmcnt(0).
// ---------------------------------------------------------------------------
__global__ __launch_bounds__(256, 3) void gemm_qkv_kernel(
    const float* __restrict__ Af, const ushort* __restrict__ Bt,
    ushort* __restrict__ C, int M, int N, int K) {
  const int tiles_n = N >> 7;
  const int nwg = gridDim.x;
  const int bid = blockIdx.x;
  const int swz = (bid & 7) * (nwg >> 3) + (bid >> 3);
  const int bm = swz / tiles_n;
  const int bn = swz % tiles_n;
  const int tid = threadIdx.x;
  const int w = tid >> 6, lane = tid & 63;
  const int wr = w >> 1, wc = w & 1;
  const int fr = lane & 15, fq = lane >> 4;

  __shared__ ushort As[3][128][32];
  __shared__ ushort Bs[3][128][32];

  f32x4 acc[4][4];
#pragma unroll
  for (int mi = 0; mi < 4; ++mi)
#pragma unroll
    for (int ni = 0; ni < 4; ++ni) acc[mi][ni] = f32x4{0.f, 0.f, 0.f, 0.f};

  // A staging: thread covers row sr, f32 cols [sh, sh+16) of each K-tile
  const int sr = tid >> 1;
  const int sh = (tid & 1) << 4;
  const float* gaf = Af + (size_t)(bm * 128 + sr) * K + sh;
  const int sw = (sr >> 1) & 3;
  const int ch0 = (((tid & 1) << 1)) ^ sw;       // stored chunk of 1st 8
  const int ch1 = (((tid & 1) << 1) + 1) ^ sw;   // stored chunk of 2nd 8
  // B staging
  const int lw = lane >> 2;
  const int scz = ((lane & 3) ^ ((lane >> 3) & 3)) << 3;
  const ushort* gb = Bt + (size_t)(bn * 128 + w * 32 + lw) * K + scz;
  const size_t rstep = (size_t)16 * K;

  const int nt = K >> 5;  // 32 (even)
  const int fqs8 = (fq ^ ((fr >> 1) & 3)) * 8;

  f32x4 pA0, pA1, pA2, pA3;   // slot even
  f32x4 qA0, qA1, qA2, qA3;   // slot odd

#define LOADA(s0, s1, s2, s3, tt)                                       \
  { const float* ap = gaf + (size_t)(tt) * 32;                          \
    s0 = *(const f32x4*)ap;       s1 = *(const f32x4*)(ap + 4);         \
    s2 = *(const f32x4*)(ap + 8); s3 = *(const f32x4*)(ap + 12); }
#define GLDB(tt)                                                        \
  { ushort* lb = &Bs[(tt) % 3][w * 32][0];                              \
    GLDS16(gb + (tt) * 32, lb);                                         \
    GLDS16(gb + (tt) * 32 + rstep, lb + 512); }
#define WRITEA(s0, s1, s2, s3, tt)                                      \
  { ushort ta[16];                                                      \
    ta[0]=f2bh(s0[0]); ta[1]=f2bh(s0[1]); ta[2]=f2bh(s0[2]); ta[3]=f2bh(s0[3]); \
    ta[4]=f2bh(s1[0]); ta[5]=f2bh(s1[1]); ta[6]=f2bh(s1[2]); ta[7]=f2bh(s1[3]); \
    ta[8]=f2bh(s2[0]); ta[9]=f2bh(s2[1]); ta[10]=f2bh(s2[2]); ta[11]=f2bh(s2[3]); \
    ta[12]=f2bh(s3[0]); ta[13]=f2bh(s3[1]); ta[14]=f2bh(s3[2]); ta[15]=f2bh(s3[3]); \
    *(short8*)&As[(tt) % 3][sr][ch0 * 8] = *(short8*)&ta[0];            \
    *(short8*)&As[(tt) % 3][sr][ch1 * 8] = *(short8*)&ta[8]; }
#define COMPUTE(tt)                                                     \
  { const int cb = (tt) % 3;                                            \
    short8 a[4], b[4];                                                  \
    _Pragma("unroll")                                                   \
    for (int mi = 0; mi < 4; ++mi)                                      \
      a[mi] = *(const short8*)&As[cb][wr * 64 + mi * 16 + fr][fqs8];    \
    _Pragma("unroll")                                                   \
    for (int ni = 0; ni < 4; ++ni)                                      \
      b[ni] = *(const short8*)&Bs[cb][wc * 64 + ni * 16 + fr][fqs8];    \
    _Pragma("unroll")                                                   \
    for (int mi = 0; mi < 4; ++mi)                                      \
      _Pragma("unroll")                                                 \
      for (int ni = 0; ni < 4; ++ni)                                    \
        acc[mi][ni] = __builtin_amdgcn_mfma_f32_16x16x32_bf16(          \
            a[mi], b[ni], acc[mi][ni], 0, 0, 0); }

  // prologue: A0,B0,A1,B1 issued; A0 forced complete; write A0; issue A2
  LOADA(pA0, pA1, pA2, pA3, 0);
  GLDB(0);
  LOADA(qA0, qA1, qA2, qA3, 1);
  GLDB(1);
  asm volatile("s_waitcnt vmcnt(8)" ::: "memory");
  WRITEA(pA0, pA1, pA2, pA3, 0);
  LOADA(pA0, pA1, pA2, pA3, 2);

  for (int t = 0; t < nt; t += 2) {
    // ---- even iter t: write A(t+1) from odd slot; reload odd slot A(t+3)
    if (t < nt - 3) {
      asm volatile("s_waitcnt vmcnt(6) lgkmcnt(0)\n\ts_barrier" ::: "memory");
    } else {
      asm volatile("s_waitcnt vmcnt(0) lgkmcnt(0)\n\ts_barrier" ::: "memory");
    }
    if (t + 1 < nt) WRITEA(qA0, qA1, qA2, qA3, t + 1);
    if (t + 3 < nt) LOADA(qA0, qA1, qA2, qA3, t + 3);
    if (t + 2 < nt) GLDB(t + 2);
    COMPUTE(t);
    // ---- odd iter t+1: write A(t+2) from even slot; reload even slot A(t+4)
    if (t + 1 < nt - 3) {
      asm volatile("s_waitcnt vmcnt(6) lgkmcnt(0)\n\ts_barrier" ::: "memory");
    } else {
      asm volatile("s_waitcnt vmcnt(0) lgkmcnt(0)\n\ts_barrier" ::: "memory");
    }
    if (t + 2 < nt) WRITEA(pA0, pA1, pA2, pA3, t + 2);
    if (t + 4 < nt) LOADA(pA0, pA1, pA2, pA3, t + 4);
    if (t + 3 < nt) GLDB(t + 3);
    COMPUTE(t + 1);
  }
#undef LOADA
#undef GLDB
#undef WRITEA
#undef COMPUTE

  // epilogue: C/D layout col=lane&15, row=(lane>>4)*4+reg
#pragma unroll
  for (int ni = 0; ni < 4; ++ni) {
    const int gc = bn * 128 + wc * 64 + ni * 16 + fr;
#pragma unroll
    for (int mi = 0; mi < 4; ++mi) {
#pragma unroll
      for (int r = 0; r < 4; ++r) {
        const int gr = bm * 128 + wr * 64 + mi * 16 + fq * 4 + r;
        C[(size_t)gr * N + gc] = f2bf(acc[mi][ni][r]);
      }
    }
  }
}

// ---------------------------------------------------------------------------
// GEMM (bf16 A): C[M][N] = A[M][K] @ Bt[N][K]^T.  BM=BN=128, BK=32,
// 256 threads, 3 LDS bufs / 2 tiles in flight, single barrier per K-step,
// counted vmcnt, XOR bank swizzle.  (out-projection)
// ---------------------------------------------------------------------------
template <bool OUT_BF16>
__global__ __launch_bounds__(256, 3) void gemm_bt_kernel(
    const ushort* __restrict__ A, const ushort* __restrict__ Bt,
    void* __restrict__ Cv, const float* __restrict__ bias,
    int M, int N, int K) {
  const int tiles_n = N >> 7;
  const int nwg = gridDim.x;
  const int bid = blockIdx.x;
  const int swz = (bid & 7) * (nwg >> 3) + (bid >> 3);
  const int bm = swz / tiles_n;
  const int bn = swz % tiles_n;
  const int tid = threadIdx.x;
  const int w = tid >> 6, lane = tid & 63;
  const int wr = w >> 1, wc = w & 1;
  const int fr = lane & 15, fq = lane >> 4;

  __shared__ ushort As[3][128][32];
  __shared__ ushort Bs[3][128][32];

  f32x4 acc[4][4];
#pragma unroll
  for (int mi = 0; mi < 4; ++mi)
#pragma unroll
    for (int ni = 0; ni < 4; ++ni) acc[mi][ni] = f32x4{0.f, 0.f, 0.f, 0.f};

  const int lw = lane >> 2;
  const int scz = ((lane & 3) ^ ((lane >> 3) & 3)) << 3;
  const ushort* ga = A + (size_t)(bm * 128 + w * 32 + lw) * K + scz;
  const ushort* gb = Bt + (size_t)(bn * 128 + w * 32 + lw) * K + scz;
  const size_t rstep = (size_t)16 * K;

  const int nt = K >> 5;

#pragma unroll
  for (int pt = 0; pt < 2; ++pt) {
    ushort* la = &As[pt][w * 32][0];
    ushort* lb = &Bs[pt][w * 32][0];
    GLDS16(ga + pt * 32, la);
    GLDS16(ga + pt * 32 + rstep, la + 512);
    GLDS16(gb + pt * 32, lb);
    GLDS16(gb + pt * 32 + rstep, lb + 512);
  }

  const int fqs8 = (fq ^ ((fr >> 1) & 3)) * 8;

  for (int t = 0; t < nt; ++t) {
    if (t < nt - 1) {
      asm volatile("s_waitcnt vmcnt(4) lgkmcnt(0)\n\ts_barrier" ::: "memory");
    } else {
      asm volatile("s_waitcnt vmcnt(0) lgkmcnt(0)\n\ts_barrier" ::: "memory");
    }
    if (t + 2 < nt) {
      const int sb = (t + 2) % 3;
      const int kt = (t + 2) << 5;
      ushort* la = &As[sb][w * 32][0];
      ushort* lb = &Bs[sb][w * 32][0];
      GLDS16(ga + kt, la);
      GLDS16(ga + kt + rstep, la + 512);
      GLDS16(gb + kt, lb);
      GLDS16(gb + kt + rstep, lb + 512);
    }
    const int cb = t % 3;
    short8 a[4], b[4];
#pragma unroll
    for (int mi = 0; mi < 4; ++mi)
      a[mi] = *(const short8*)&As[cb][wr * 64 + mi * 16 + fr][fqs8];
#pragma unroll
    for (int ni = 0; ni < 4; ++ni)
      b[ni] = *(const short8*)&Bs[cb][wc * 64 + ni * 16 + fr][fqs8];
#pragma unroll
    for (int mi = 0; mi < 4; ++mi)
#pragma unroll
      for (int ni = 0; ni < 4; ++ni)
        acc[mi][ni] = __builtin_amdgcn_mfma_f32_16x16x32_bf16(
            a[mi], b[ni], acc[mi][ni], 0, 0, 0);
  }

#pragma unroll
  for (int ni = 0; ni < 4; ++ni) {
    const int gc = bn * 128 + wc * 64 + ni * 16 + fr;
    float badd = (!OUT_BF16 && bias) ? bias[gc] : 0.f;
#pragma unroll
    for (int mi = 0; mi < 4; ++mi) {
#pragma unroll
      for (int r = 0; r < 4; ++r) {
        const int gr = bm * 128 + wr * 64 + mi * 16 + fq * 4 + r;
        if (OUT_BF16) {
          ((ushort*)Cv)[(size_t)gr * N + gc] = f2bf(acc[mi][ni][r]);
        } else {
          ((float*)Cv)[(size_t)gr * N + gc] = acc[mi][ni][r] + badd;
        }
      }
    }
  }
}

// ---------------------------------------------------------------------------
// intraS: per (b,h,chunk) compute S_c = ETA*cl * K^T @ (V/cum)  (bf16 out).
// ---------------------------------------------------------------------------
__global__ __launch_bounds__(256) void intraS_kernel(
    const ushort* __restrict__ qkv, const float* __restrict__ gamma,
    ushort* __restrict__ S, float* __restrict__ clb) {
  const int bx = blockIdx.x;
  const int c = bx & (NCH - 1);
  const int h = (bx >> 5) & (NH - 1);
  const int b = bx >> 8;
  const int tid = threadIdx.x;
  const int w = tid >> 6, lane = tid & 63;
  const int fr = lane & 15, fq = lane >> 4;

  __shared__ ushort KT[64][72];
  __shared__ ushort VT[64][72];
  __shared__ float cumS[64];

  const int p = tid >> 2, d0 = (tid & 3) * 16;
  const ushort* base = &qkv[((size_t)b * SEQ + c * CH + p) * QKVW + h * 64 + d0];
  short8 k0 = *(const short8*)(base + 512);
  short8 k1 = *(const short8*)(base + 520);
  short8 v0 = *(const short8*)(base + 1024);
  short8 v1 = *(const short8*)(base + 1032);

  {
    float g = gamma[(size_t)b * SEQ + c * CH + lane];
    float prod = expf(-fminf(g, 10.f));
#pragma unroll
    for (int off = 1; off < 64; off <<= 1) {
      float o = __shfl_up(prod, off);
      if (lane >= off) prod *= o;
    }
    cumS[lane] = prod;
  }
  __syncthreads();

  {
    const float rc = 1.f / cumS[p];
#pragma unroll
    for (int j = 0; j < 8; ++j) {
      KT[d0 + j][p] = (ushort)k0[j];
      KT[d0 + 8 + j][p] = (ushort)k1[j];
      VT[d0 + j][p] = f2bf(bf2f((ushort)v0[j]) * rc);
      VT[d0 + 8 + j][p] = f2bf(bf2f((ushort)v1[j]) * rc);
    }
  }
  __syncthreads();

  const float scl = ETA * cumS[63];
  const int arow = w * 16 + fr;
  short8 ka0 = *(const short8*)&KT[arow][fq * 8];
  short8 ka1 = *(const short8*)&KT[arow][32 + fq * 8];
  ushort* Sp = &S[(((size_t)(b * NH + h)) * NCH + c) << 12];
#pragma unroll
  for (int cf = 0; cf < 4; ++cf) {
    short8 bv0 = *(const short8*)&VT[cf * 16 + fr][fq * 8];
    short8 bv1 = *(const short8*)&VT[cf * 16 + fr][32 + fq * 8];
    f32x4 accS = {0.f, 0.f, 0.f, 0.f};
    accS = __builtin_amdgcn_mfma_f32_16x16x32_bf16(ka0, bv0, accS, 0, 0, 0);
    accS = __builtin_amdgcn_mfma_f32_16x16x32_bf16(ka1, bv1, accS, 0, 0, 0);
#pragma unroll
    for (int r = 0; r < 4; ++r) {
      int row = w * 16 + fq * 4 + r;
      int col = cf * 16 + fr;
      Sp[row * 64 + col] = f2bf(accS[r] * scl);
    }
  }
  if (tid == 0 && h == 0) clb[b * NCH + c] = cumS[63];
}

// ---------------------------------------------------------------------------
// prop: stash[c] = st (before chunk c, bf16); st = cl[c]*st + S_c
// ---------------------------------------------------------------------------
__global__ __launch_bounds__(256) void prop_kernel(
    const float* __restrict__ state0, const ushort* __restrict__ S,
    const float* __restrict__ clb, ushort* __restrict__ stash,
    float* __restrict__ state_out) {
  const int bh = blockIdx.x >> 2, rg = blockIdx.x & 3;
  const int b = bh >> 3;
  const int tid = threadIdx.x;
  const int i = rg * 16 + (tid >> 4);
  const int j0 = (tid & 15) * 4;
  const size_t off = ((size_t)bh * 64 + i) * 64 + j0;
  const size_t coff = (size_t)i * 64 + j0;

  f32x4 st = *(const f32x4*)&state0[off];
#pragma unroll 4
  for (int c = 0; c < NCH; ++c) {
    const size_t base = (((size_t)bh * NCH + c) << 12) + coff;
    short4v sv;
#pragma unroll
    for (int e = 0; e < 4; ++e) sv[e] = (short)f2bf(st[e]);
    *(short4v*)&stash[base] = sv;
    short4v s = *(const short4v*)&S[base];
    float clv = clb[b * NCH + c];
#pragma unroll
    for (int e = 0; e < 4; ++e) st[e] = st[e] * clv + bf2f((ushort)s[e]);
  }
  *(f32x4*)&state_out[off] = st;
}

// ---------------------------------------------------------------------------
// intraY: P = mask(cum*q @ (v/cum)^T)*ETA ; y = P @ K + (cum*q) @ stash^T
// ---------------------------------------------------------------------------
__global__ __launch_bounds__(256) void intraY_kernel(
    const ushort* __restrict__ qkv, const float* __restrict__ gamma,
    const ushort* __restrict__ stash, ushort* __restrict__ ybf) {
  const int bx = blockIdx.x;
  const int c = bx & (NCH - 1);
  const int h = (bx >> 5) & (NH - 1);
  const int b = bx >> 8;
  const int tid = threadIdx.x;
  const int w = tid >> 6, lane = tid & 63;
  const int fr = lane & 15, fq = lane >> 4;

  __shared__ ushort Qs[64][72];
  __shared__ ushort Vs[64][72];
  __shared__ ushort KT[64][72];
  __shared__ ushort Ps[64][72];
  __shared__ ushort Bst[64][72];
  __shared__ float cumS[64];

  const int p = tid >> 2, d0 = (tid & 3) * 16;
  const ushort* base = &qkv[((size_t)b * SEQ + c * CH + p) * QKVW + h * 64 + d0];
  short8 q0 = *(const short8*)base;
  short8 q1 = *(const short8*)(base + 8);
  short8 k0 = *(const short8*)(base + 512);
  short8 k1 = *(const short8*)(base + 520);
  short8 v0 = *(const short8*)(base + 1024);
  short8 v1 = *(const short8*)(base + 1032);
  const size_t sb = ((((size_t)(b * NH + h)) * NCH + c) << 12) + (size_t)p * 64 + d0;
  short8 s0 = *(const short8*)&stash[sb];
  short8 s1 = *(const short8*)&stash[sb + 8];

  {
    float g = gamma[(size_t)b * SEQ + c * CH + lane];
    float prod = expf(-fminf(g, 10.f));
#pragma unroll
    for (int off = 1; off < 64; off <<= 1) {
      float o = __shfl_up(prod, off);
      if (lane >= off) prod *= o;
    }
    cumS[lane] = prod;
  }
  __syncthreads();

  {
    const float cp = cumS[p];
    const float rc = 1.f / cp;
    ushort tq[16], tv[16];
#pragma unroll
    for (int j = 0; j < 8; ++j) {
      tq[j]     = f2bf(bf2f((ushort)q0[j]) * cp);
      tq[8 + j] = f2bf(bf2f((ushort)q1[j]) * cp);
      tv[j]     = f2bf(bf2f((ushort)v0[j]) * rc);
      tv[8 + j] = f2bf(bf2f((ushort)v1[j]) * rc);
      KT[d0 + j][p] = (ushort)k0[j];
      KT[d0 + 8 + j][p] = (ushort)k1[j];
    }
    *(short8*)&Qs[p][d0] = *(short8*)&tq[0];
    *(short8*)&Qs[p][d0 + 8] = *(short8*)&tq[8];
    *(short8*)&Vs[p][d0] = *(short8*)&tv[0];
    *(short8*)&Vs[p][d0 + 8] = *(short8*)&tv[8];
    *(short8*)&Bst[p][d0] = s0;
    *(short8*)&Bst[p][d0 + 8] = s1;
  }
  __syncthreads();

  const int arow = w * 16 + fr;
  short8 a0 = *(const short8*)&Qs[arow][fq * 8];
  short8 a1 = *(const short8*)&Qs[arow][32 + fq * 8];

#pragma unroll
  for (int cf = 0; cf < 4; ++cf) {
    f32x4 acc = {0.f, 0.f, 0.f, 0.f};
    if (cf <= w) {
      short8 b0 = *(const short8*)&Vs[cf * 16 + fr][fq * 8];
      short8 b1 = *(const short8*)&Vs[cf * 16 + fr][32 + fq * 8];
      acc = __builtin_amdgcn_mfma_f32_16x16x32_bf16(a0, b0, acc, 0, 0, 0);
      acc = __builtin_amdgcn_mfma_f32_16x16x32_bf16(a1, b1, acc, 0, 0, 0);
    }
#pragma unroll
    for (int r = 0; r < 4; ++r) {
      int pi = w * 16 + fq * 4 + r, si = cf * 16 + fr;
      Ps[pi][si] = f2bf((si <= pi) ? acc[r] * ETA : 0.f);
    }
  }
  __syncthreads();

  short8 p0 = *(const short8*)&Ps[arow][fq * 8];
  short8 p1 = *(const short8*)&Ps[arow][32 + fq * 8];
  const size_t yrow0 = (size_t)b * SEQ + c * CH;
#pragma unroll
  for (int cf = 0; cf < 4; ++cf) {
    f32x4 accY = {0.f, 0.f, 0.f, 0.f};
    short8 bs0 = *(const short8*)&Bst[cf * 16 + fr][fq * 8];
    short8 bs1 = *(const short8*)&Bst[cf * 16 + fr][32 + fq * 8];
    accY = __builtin_amdgcn_mfma_f32_16x16x32_bf16(a0, bs0, accY, 0, 0, 0);
    accY = __builtin_amdgcn_mfma_f32_16x16x32_bf16(a1, bs1, accY, 0, 0, 0);
    short8 bk0 = *(const short8*)&KT[cf * 16 + fr][fq * 8];
    short8 bk1 = *(const short8*)&KT[cf * 16 + fr][32 + fq * 8];
    accY = __builtin_amdgcn_mfma_f32_16x16x32_bf16(p0, bk0, accY, 0, 0, 0);
    accY = __builtin_amdgcn_mfma_f32_16x16x32_bf16(p1, bk1, accY, 0, 0, 0);
#pragma unroll
    for (int r = 0; r < 4; ++r) {
      int row = w * 16 + fq * 4 + r;
      int col = cf * 16 + fr;
      ybf[(yrow0 + row) * HD + h * 64 + col] = f2bf(accY[r]);
    }
  }
}

extern "C" void kernel_launch(void* const* d_in, const int* in_sizes, int n_in,
                              void* d_out, int out_size, void* d_ws, size_t ws_size,
                              hipStream_t stream) {
  const float* x      = (const float*)d_in[0];
  const float* gamma  = (const float*)d_in[1];
  const float* state0 = (const float*)d_in[2];
  const float* Wq     = (const float*)d_in[3];
  const float* Wk     = (const float*)d_in[4];
  const float* Wv     = (const float*)d_in[5];
  const float* Wo     = (const float*)d_in[6];
  const float* bo     = (const float*)d_in[7];

  float* out = (float*)d_out;
  float* state_out = out + (size_t)BATCH * SEQ * DMODEL;

  const int M = BATCH * SEQ;  // 8192

  ushort* wt  = (ushort*)d_ws;                       // [1536][1024]
  ushort* wot = wt + (size_t)QKVW * DMODEL;          // [1024][512]
  ushort* qkv = wot + (size_t)DMODEL * HD;           // [8192][1536]
  ushort* ybf = qkv + (size_t)M * QKVW;              // [8192][512]
  ushort* Sb  = ybf + (size_t)M * HD;                // [32][32][4096] bf16
  ushort* stash = Sb + (size_t)BATCH * NH * NCH * 4096;
  float*  clb   = (float*)(stash + (size_t)BATCH * NH * NCH * 4096);

  dim3 blk(256);

  conv_kernel<<<dim3(2048), blk, 0, stream>>>(Wq, Wk, Wv, Wo, wt, wot);

  gemm_qkv_kernel<<<dim3((M / 128) * (QKVW / 128)), blk, 0, stream>>>(
      x, wt, qkv, M, QKVW, DMODEL);

  intraS_kernel<<<dim3(BATCH * NH * NCH), blk, 0, stream>>>(
      qkv, gamma, Sb, clb);
  prop_kernel<<<dim3(BATCH * NH * 4), blk, 0, stream>>>(
      state0, Sb, clb, stash, state_out);
  intraY_kernel<<<dim3(BATCH * NH * NCH), blk, 0, stream>>>(
      qkv, gamma, stash, ybf);

  gemm_bt_kernel<false><<<dim3((M / 128) * (DMODEL / 128)), blk, 0, stream>>>(
      ybf, wot, out, bo, M, DMODEL, HD);
}

// Round 10
// 92.107 us; speedup vs baseline: 1.0409x; 1.0246x over previous
//
#include <hip/hip_runtime.h>

#define ETA 0.1f
#define BATCH 4
#define SEQ 2048
#define DMODEL 1024
#define NH 8
#define DHEAD 64
#define HD 512   // NH*DHEAD
#define QKVW 1536
#define CH 64    // chunk length
#define NCH (SEQ / CH)  // 32

typedef float f32x4 __attribute__((ext_vector_type(4)));
typedef short short8 __attribute__((ext_vector_type(8)));
typedef short short4v __attribute__((ext_vector_type(4)));

static __device__ __forceinline__ ushort f2bf(float f) {
  union { float f; unsigned u; } x; x.f = f;
  unsigned r = (x.u + 0x7fffu + ((x.u >> 16) & 1u)) >> 16;
  return (ushort)r;
}
static __device__ __forceinline__ float bf2f(ushort u) {
  union { unsigned u; float f; } x; x.u = ((unsigned)u) << 16;
  return x.f;
}

#define GLDS16(g, l)                                                    \
  __builtin_amdgcn_global_load_lds(                                     \
      (const __attribute__((address_space(1))) unsigned int*)(const void*)(g), \
      (__attribute__((address_space(3))) unsigned int*)(void*)(l), 16, 0, 0)

// ---------------------------------------------------------------------------
// conv: merged input/weight conversion.
//   blocks [0,2048): x f32 -> xb bf16 (16 elems/thread)
//   blocks [2048,4096): weight transpose+convert (Wq/Wk/Wv -> Wt, Wo -> Wot)
// ---------------------------------------------------------------------------
__global__ __launch_bounds__(256) void conv_kernel(
    const float* __restrict__ x, const float* __restrict__ Wq,
    const float* __restrict__ Wk, const float* __restrict__ Wv,
    const float* __restrict__ Wo, ushort* __restrict__ xb,
    ushort* __restrict__ Wt, ushort* __restrict__ Wot) {
  const int tid = threadIdx.x;
  __shared__ float T[32][33];
  if (blockIdx.x < 2048) {
    size_t i = ((size_t)blockIdx.x * 256 + tid) * 16;
    ushort t[16];
#pragma unroll
    for (int u = 0; u < 4; ++u) {
      f32x4 v = *(const f32x4*)&x[i + u * 4];
#pragma unroll
      for (int e = 0; e < 4; ++e) t[u * 4 + e] = f2bf(v[e]);
    }
    *(short8*)&xb[i] = *(short8*)&t[0];
    *(short8*)&xb[i + 8] = *(short8*)&t[8];
    return;
  }
  const int idx = blockIdx.x - 2048;
  const int m = idx >> 9;          // 0..3
  const int bx = idx & 511;
  const float* src;
  ushort* dst;
  int srcN, dstK, k0, n0, rowOff;
  if (m < 3) {
    src = (m == 0) ? Wq : ((m == 1) ? Wk : Wv);
    srcN = 512; dstK = 1024;
    k0 = (bx >> 4) << 5; n0 = (bx & 15) << 5;
    dst = Wt; rowOff = m * 512;
  } else {
    src = Wo; srcN = 1024; dstK = 512;
    k0 = (bx >> 5) << 5; n0 = (bx & 31) << 5;
    dst = Wot; rowOff = 0;
  }
  const int r = tid >> 3, c4 = (tid & 7) << 2;
  f32x4 v = *(const f32x4*)&src[(size_t)(k0 + r) * srcN + n0 + c4];
  T[r][c4 + 0] = v[0]; T[r][c4 + 1] = v[1];
  T[r][c4 + 2] = v[2]; T[r][c4 + 3] = v[3];
  __syncthreads();
  short4v o;
#pragma unroll
  for (int e = 0; e < 4; ++e) o[e] = (short)f2bf(T[c4 + e][r]);
  *(short4v*)&dst[(size_t)(rowOff + n0 + r) * dstK + k0 + c4] = o;
}

// ---------------------------------------------------------------------------
// GEMM: C[M][N] = A[M][K] @ Bt[N][K]^T, bf16 in.  BM=BN=128, BK=32,
// 256 threads (4 waves, 2x2), 3 LDS buffers / 2 tiles in flight,
// single barrier per K-step, counted vmcnt, XOR bank swizzle.
// ---------------------------------------------------------------------------
template <bool OUT_BF16>
__global__ __launch_bounds__(256, 3) void gemm_bt_kernel(
    const ushort* __restrict__ A, const ushort* __restrict__ Bt,
    void* __restrict__ Cv, const float* __restrict__ bias,
    int M, int N, int K) {
  const int tiles_n = N >> 7;
  const int nwg = gridDim.x;
  const int bid = blockIdx.x;
  const int swz = (bid & 7) * (nwg >> 3) + (bid >> 3);
  const int bm = swz / tiles_n;
  const int bn = swz % tiles_n;
  const int tid = threadIdx.x;
  const int w = tid >> 6, lane = tid & 63;
  const int wr = w >> 1, wc = w & 1;
  const int fr = lane & 15, fq = lane >> 4;

  __shared__ ushort As[3][128][32];
  __shared__ ushort Bs[3][128][32];

  f32x4 acc[4][4];
#pragma unroll
  for (int mi = 0; mi < 4; ++mi)
#pragma unroll
    for (int ni = 0; ni < 4; ++ni) acc[mi][ni] = f32x4{0.f, 0.f, 0.f, 0.f};

  const int lw = lane >> 2;
  const int scz = ((lane & 3) ^ ((lane >> 3) & 3)) << 3;
  const ushort* ga = A + (size_t)(bm * 128 + w * 32 + lw) * K + scz;
  const ushort* gb = Bt + (size_t)(bn * 128 + w * 32 + lw) * K + scz;
  const size_t rstep = (size_t)16 * K;

  const int nt = K >> 5;

#pragma unroll
  for (int pt = 0; pt < 2; ++pt) {
    ushort* la = &As[pt][w * 32][0];
    ushort* lb = &Bs[pt][w * 32][0];
    GLDS16(ga + pt * 32, la);
    GLDS16(ga + pt * 32 + rstep, la + 512);
    GLDS16(gb + pt * 32, lb);
    GLDS16(gb + pt * 32 + rstep, lb + 512);
  }

  const int fqs8 = (fq ^ ((fr >> 1) & 3)) * 8;

  for (int t = 0; t < nt; ++t) {
    if (t < nt - 1) {
      asm volatile("s_waitcnt vmcnt(4) lgkmcnt(0)\n\ts_barrier" ::: "memory");
    } else {
      asm volatile("s_waitcnt vmcnt(0) lgkmcnt(0)\n\ts_barrier" ::: "memory");
    }
    if (t + 2 < nt) {
      const int sb = (t + 2) % 3;
      const int kt = (t + 2) << 5;
      ushort* la = &As[sb][w * 32][0];
      ushort* lb = &Bs[sb][w * 32][0];
      GLDS16(ga + kt, la);
      GLDS16(ga + kt + rstep, la + 512);
      GLDS16(gb + kt, lb);
      GLDS16(gb + kt + rstep, lb + 512);
    }
    const int cb = t % 3;
    short8 a[4], b[4];
#pragma unroll
    for (int mi = 0; mi < 4; ++mi)
      a[mi] = *(const short8*)&As[cb][wr * 64 + mi * 16 + fr][fqs8];
#pragma unroll
    for (int ni = 0; ni < 4; ++ni)
      b[ni] = *(const short8*)&Bs[cb][wc * 64 + ni * 16 + fr][fqs8];
#pragma unroll
    for (int mi = 0; mi < 4; ++mi)
#pragma unroll
      for (int ni = 0; ni < 4; ++ni)
        acc[mi][ni] = __builtin_amdgcn_mfma_f32_16x16x32_bf16(
            a[mi], b[ni], acc[mi][ni], 0, 0, 0);
  }

#pragma unroll
  for (int ni = 0; ni < 4; ++ni) {
    const int gc = bn * 128 + wc * 64 + ni * 16 + fr;
    float badd = (!OUT_BF16 && bias) ? bias[gc] : 0.f;
#pragma unroll
    for (int mi = 0; mi < 4; ++mi) {
#pragma unroll
      for (int r = 0; r < 4; ++r) {
        const int gr = bm * 128 + wr * 64 + mi * 16 + fq * 4 + r;
        if (OUT_BF16) {
          ((ushort*)Cv)[(size_t)gr * N + gc] = f2bf(acc[mi][ni][r]);
        } else {
          ((float*)Cv)[(size_t)gr * N + gc] = acc[mi][ni][r] + badd;
        }
      }
    }
  }
}

// ---------------------------------------------------------------------------
// intraS: per (b,h,chunk) compute S_c = ETA*cl * K^T @ (V/cum)  (bf16 out).
// ---------------------------------------------------------------------------
__global__ __launch_bounds__(256) void intraS_kernel(
    const ushort* __restrict__ qkv, const float* __restrict__ gamma,
    ushort* __restrict__ S, float* __restrict__ clb) {
  const int bx = blockIdx.x;
  const int c = bx & (NCH - 1);
  const int h = (bx >> 5) & (NH - 1);
  const int b = bx >> 8;
  const int tid = threadIdx.x;
  const int w = tid >> 6, lane = tid & 63;
  const int fr = lane & 15, fq = lane >> 4;

  __shared__ ushort KT[64][72];
  __shared__ ushort VT[64][72];
  __shared__ float cumS[64];

  const int p = tid >> 2, d0 = (tid & 3) * 16;
  const ushort* base = &qkv[((size_t)b * SEQ + c * CH + p) * QKVW + h * 64 + d0];
  short8 k0 = *(const short8*)(base + 512);
  short8 k1 = *(const short8*)(base + 520);
  short8 v0 = *(const short8*)(base + 1024);
  short8 v1 = *(const short8*)(base + 1032);

  {
    float g = gamma[(size_t)b * SEQ + c * CH + lane];
    float prod = expf(-fminf(g, 10.f));
#pragma unroll
    for (int off = 1; off < 64; off <<= 1) {
      float o = __shfl_up(prod, off);
      if (lane >= off) prod *= o;
    }
    cumS[lane] = prod;
  }
  __syncthreads();

  {
    const float rc = 1.f / cumS[p];
#pragma unroll
    for (int j = 0; j < 8; ++j) {
      KT[d0 + j][p] = (ushort)k0[j];
      KT[d0 + 8 + j][p] = (ushort)k1[j];
      VT[d0 + j][p] = f2bf(bf2f((ushort)v0[j]) * rc);
      VT[d0 + 8 + j][p] = f2bf(bf2f((ushort)v1[j]) * rc);
    }
  }
  __syncthreads();

  const float scl = ETA * cumS[63];
  const int arow = w * 16 + fr;
  short8 ka0 = *(const short8*)&KT[arow][fq * 8];
  short8 ka1 = *(const short8*)&KT[arow][32 + fq * 8];
  ushort* Sp = &S[(((size_t)(b * NH + h)) * NCH + c) << 12];
  __builtin_amdgcn_s_setprio(1);
#pragma unroll
  for (int cf = 0; cf < 4; ++cf) {
    short8 bv0 = *(const short8*)&VT[cf * 16 + fr][fq * 8];
    short8 bv1 = *(const short8*)&VT[cf * 16 + fr][32 + fq * 8];
    f32x4 accS = {0.f, 0.f, 0.f, 0.f};
    accS = __builtin_amdgcn_mfma_f32_16x16x32_bf16(ka0, bv0, accS, 0, 0, 0);
    accS = __builtin_amdgcn_mfma_f32_16x16x32_bf16(ka1, bv1, accS, 0, 0, 0);
#pragma unroll
    for (int r = 0; r < 4; ++r) {
      int row = w * 16 + fq * 4 + r;
      int col = cf * 16 + fr;
      Sp[row * 64 + col] = f2bf(accS[r] * scl);
    }
  }
  __builtin_amdgcn_s_setprio(0);
  if (tid == 0 && h == 0) clb[b * NCH + c] = cumS[63];
}

// ---------------------------------------------------------------------------
// prop: stash[c] = st (before chunk c, bf16); st = cl[c]*st + S_c
// ---------------------------------------------------------------------------
__global__ __launch_bounds__(256) void prop_kernel(
    const float* __restrict__ state0, const ushort* __restrict__ S,
    const float* __restrict__ clb, ushort* __restrict__ stash,
    float* __restrict__ state_out) {
  const int bh = blockIdx.x >> 2, rg = blockIdx.x & 3;
  const int b = bh >> 3;
  const int tid = threadIdx.x;
  const int i = rg * 16 + (tid >> 4);
  const int j0 = (tid & 15) * 4;
  const size_t off = ((size_t)bh * 64 + i) * 64 + j0;
  const size_t coff = (size_t)i * 64 + j0;

  f32x4 st = *(const f32x4*)&state0[off];
#pragma unroll 4
  for (int c = 0; c < NCH; ++c) {
    const size_t base = (((size_t)bh * NCH + c) << 12) + coff;
    short4v sv;
#pragma unroll
    for (int e = 0; e < 4; ++e) sv[e] = (short)f2bf(st[e]);
    *(short4v*)&stash[base] = sv;
    short4v s = *(const short4v*)&S[base];
    float clv = clb[b * NCH + c];
#pragma unroll
    for (int e = 0; e < 4; ++e) st[e] = st[e] * clv + bf2f((ushort)s[e]);
  }
  *(f32x4*)&state_out[off] = st;
}

// ---------------------------------------------------------------------------
// intraY: P = mask(cum*q @ (v/cum)^T)*ETA ; y = P @ K + (cum*q) @ stash^T
// ---------------------------------------------------------------------------
__global__ __launch_bounds__(256) void intraY_kernel(
    const ushort* __restrict__ qkv, const float* __restrict__ gamma,
    const ushort* __restrict__ stash, ushort* __restrict__ ybf) {
  const int bx = blockIdx.x;
  const int c = bx & (NCH - 1);
  const int h = (bx >> 5) & (NH - 1);
  const int b = bx >> 8;
  const int tid = threadIdx.x;
  const int w = tid >> 6, lane = tid & 63;
  const int fr = lane & 15, fq = lane >> 4;

  __shared__ ushort Qs[64][72];
  __shared__ ushort Vs[64][72];
  __shared__ ushort KT[64][72];
  __shared__ ushort Ps[64][72];
  __shared__ ushort Bst[64][72];
  __shared__ float cumS[64];

  const int p = tid >> 2, d0 = (tid & 3) * 16;
  const ushort* base = &qkv[((size_t)b * SEQ + c * CH + p) * QKVW + h * 64 + d0];
  short8 q0 = *(const short8*)base;
  short8 q1 = *(const short8*)(base + 8);
  short8 k0 = *(const short8*)(base + 512);
  short8 k1 = *(const short8*)(base + 520);
  short8 v0 = *(const short8*)(base + 1024);
  short8 v1 = *(const short8*)(base + 1032);
  const size_t sb = ((((size_t)(b * NH + h)) * NCH + c) << 12) + (size_t)p * 64 + d0;
  short8 s0 = *(const short8*)&stash[sb];
  short8 s1 = *(const short8*)&stash[sb + 8];

  {
    float g = gamma[(size_t)b * SEQ + c * CH + lane];
    float prod = expf(-fminf(g, 10.f));
#pragma unroll
    for (int off = 1; off < 64; off <<= 1) {
      float o = __shfl_up(prod, off);
      if (lane >= off) prod *= o;
    }
    cumS[lane] = prod;
  }
  __syncthreads();

  {
    const float cp = cumS[p];
    const float rc = 1.f / cp;
    ushort tq[16], tv[16];
#pragma unroll
    for (int j = 0; j < 8; ++j) {
      tq[j]     = f2bf(bf2f((ushort)q0[j]) * cp);
      tq[8 + j] = f2bf(bf2f((ushort)q1[j]) * cp);
      tv[j]     = f2bf(bf2f((ushort)v0[j]) * rc);
      tv[8 + j] = f2bf(bf2f((ushort)v1[j]) * rc);
      KT[d0 + j][p] = (ushort)k0[j];
      KT[d0 + 8 + j][p] = (ushort)k1[j];
    }
    *(short8*)&Qs[p][d0] = *(short8*)&tq[0];
    *(short8*)&Qs[p][d0 + 8] = *(short8*)&tq[8];
    *(short8*)&Vs[p][d0] = *(short8*)&tv[0];
    *(short8*)&Vs[p][d0 + 8] = *(short8*)&tv[8];
    *(short8*)&Bst[p][d0] = s0;
    *(short8*)&Bst[p][d0 + 8] = s1;
  }
  __syncthreads();

  const int arow = w * 16 + fr;
  short8 a0 = *(const short8*)&Qs[arow][fq * 8];
  short8 a1 = *(const short8*)&Qs[arow][32 + fq * 8];

  __builtin_amdgcn_s_setprio(1);
#pragma unroll
  for (int cf = 0; cf < 4; ++cf) {
    f32x4 acc = {0.f, 0.f, 0.f, 0.f};
    if (cf <= w) {
      short8 b0 = *(const short8*)&Vs[cf * 16 + fr][fq * 8];
      short8 b1 = *(const short8*)&Vs[cf * 16 + fr][32 + fq * 8];
      acc = __builtin_amdgcn_mfma_f32_16x16x32_bf16(a0, b0, acc, 0, 0, 0);
      acc = __builtin_amdgcn_mfma_f32_16x16x32_bf16(a1, b1, acc, 0, 0, 0);
    }
#pragma unroll
    for (int r = 0; r < 4; ++r) {
      int pi = w * 16 + fq * 4 + r, si = cf * 16 + fr;
      Ps[pi][si] = f2bf((si <= pi) ? acc[r] * ETA : 0.f);
    }
  }
  __builtin_amdgcn_s_setprio(0);
  __syncthreads();

  short8 p0 = *(const short8*)&Ps[arow][fq * 8];
  short8 p1 = *(const short8*)&Ps[arow][32 + fq * 8];
  const size_t yrow0 = (size_t)b * SEQ + c * CH;
  __builtin_amdgcn_s_setprio(1);
#pragma unroll
  for (int cf = 0; cf < 4; ++cf) {
    f32x4 accY = {0.f, 0.f, 0.f, 0.f};
    short8 bs0 = *(const short8*)&Bst[cf * 16 + fr][fq * 8];
    short8 bs1 = *(const short8*)&Bst[cf * 16 + fr][32 + fq * 8];
    accY = __builtin_amdgcn_mfma_f32_16x16x32_bf16(a0, bs0, accY, 0, 0, 0);
    accY = __builtin_amdgcn_mfma_f32_16x16x32_bf16(a1, bs1, accY, 0, 0, 0);
    short8 bk0 = *(const short8*)&KT[cf * 16 + fr][fq * 8];
    short8 bk1 = *(const short8*)&KT[cf * 16 + fr][32 + fq * 8];
    accY = __builtin_amdgcn_mfma_f32_16x16x32_bf16(p0, bk0, accY, 0, 0, 0);
    accY = __builtin_amdgcn_mfma_f32_16x16x32_bf16(p1, bk1, accY, 0, 0, 0);
#pragma unroll
    for (int r = 0; r < 4; ++r) {
      int row = w * 16 + fq * 4 + r;
      int col = cf * 16 + fr;
      ybf[(yrow0 + row) * HD + h * 64 + col] = f2bf(accY[r]);
    }
  }
  __builtin_amdgcn_s_setprio(0);
}

extern "C" void kernel_launch(void* const* d_in, const int* in_sizes, int n_in,
                              void* d_out, int out_size, void* d_ws, size_t ws_size,
                              hipStream_t stream) {
  const float* x      = (const float*)d_in[0];
  const float* gamma  = (const float*)d_in[1];
  const float* state0 = (const float*)d_in[2];
  const float* Wq     = (const float*)d_in[3];
  const float* Wk     = (const float*)d_in[4];
  const float* Wv     = (const float*)d_in[5];
  const float* Wo     = (const float*)d_in[6];
  const float* bo     = (const float*)d_in[7];

  float* out = (float*)d_out;
  float* state_out = out + (size_t)BATCH * SEQ * DMODEL;

  const int M = BATCH * SEQ;  // 8192

  ushort* xb  = (ushort*)d_ws;                       // [8192][1024]
  ushort* wt  = xb + (size_t)M * DMODEL;             // [1536][1024]
  ushort* wot = wt + (size_t)QKVW * DMODEL;          // [1024][512]
  ushort* qkv = wot + (size_t)DMODEL * HD;           // [8192][1536]
  ushort* ybf = qkv + (size_t)M * QKVW;              // [8192][512]
  ushort* Sb  = ybf + (size_t)M * HD;                // [32][32][4096] bf16
  ushort* stash = Sb + (size_t)BATCH * NH * NCH * 4096;
  float*  clb   = (float*)(stash + (size_t)BATCH * NH * NCH * 4096);

  dim3 blk(256);

  conv_kernel<<<dim3(4096), blk, 0, stream>>>(x, Wq, Wk, Wv, Wo, xb, wt, wot);

  gemm_bt_kernel<true><<<dim3((M / 128) * (QKVW / 128)), blk, 0, stream>>>(
      xb, wt, qkv, nullptr, M, QKVW, DMODEL);

  intraS_kernel<<<dim3(BATCH * NH * NCH), blk, 0, stream>>>(
      qkv, gamma, Sb, clb);
  prop_kernel<<<dim3(BATCH * NH * 4), blk, 0, stream>>>(
      state0, Sb, clb, stash, state_out);
  intraY_kernel<<<dim3(BATCH * NH * NCH), blk, 0, stream>>>(
      qkv, gamma, stash, ybf);

  gemm_bt_kernel<false><<<dim3((M / 128) * (DMODEL / 128)), blk, 0, stream>>>(
      ybf, wot, out, bo, M, DMODEL, HD);
}